// Round 3
// baseline (6237.813 us; speedup 1.0000x reference)
//
#include <hip/hip_runtime.h>
#include <hip/hip_bf16.h>

// Problem constants
#define BB 2
#define TT 12
#define NN 20000
#define FF 9
#define HH 64
#define EE 200000

#define MODE_F32  1
#define MODE_BF16 2

__device__ __forceinline__ float ldin(const float* p, long i){ return p[i]; }
__device__ __forceinline__ float ldin(const __hip_bfloat16* p, long i){ return __bfloat162float(p[i]); }
__device__ __forceinline__ void stout(float* p, long i, float v){ p[i] = v; }
__device__ __forceinline__ void stout(__hip_bfloat16* p, long i, float v){ p[i] = __float2bfloat16(v); }

// ---- dtype probe: edge_weight ~ U[0,1). If packed bf16, bit15 of every u32
// is a bf16 sign bit (=0). If fp32, bit15 is a random mantissa bit. ---------
__global__ void k_probe(const unsigned* __restrict__ ew_bits, int* __restrict__ flag){
  if(threadIdx.x==0 && blockIdx.x==0){
    unsigned any = 0;
    for(int i=0;i<1000;i++) any |= ew_bits[i];   // 4000B — safe for both dtypes
    *flag = (any & 0x8000u) ? MODE_F32 : MODE_BF16;
  }
}

// ---- CSR build (dtype-free) ----------------------------------------------
__global__ void k_count(const int* __restrict__ dst, int* __restrict__ counts){
  int e = blockIdx.x*256 + threadIdx.x;
  if(e < EE) atomicAdd(&counts[dst[e]], 1);
}

__global__ void k_scan(const int* __restrict__ counts, int* __restrict__ row_ptr){
  __shared__ int part[256];
  const int CH = 79;                       // 256*79 = 20224 >= 20000
  int t = threadIdx.x;
  int base = t*CH;
  int s = 0;
  for(int i=0;i<CH;i++){ int idx=base+i; if(idx<NN) s += counts[idx]; }
  part[t] = s; __syncthreads();
  for(int off=1; off<256; off<<=1){
    int v = (t>=off) ? part[t-off] : 0;
    __syncthreads();
    part[t] += v;
    __syncthreads();
  }
  int run = (t==0) ? 0 : part[t-1];
  for(int i=0;i<CH;i++){
    int idx=base+i;
    if(idx<NN){ run += counts[idx]; row_ptr[idx+1] = run; }
  }
  if(t==0) row_ptr[0] = 0;
}

__global__ void k_fill(const int* __restrict__ dst, const int* __restrict__ row_ptr,
                       int* __restrict__ cursor, int* __restrict__ eidx){
  int e = blockIdx.x*256 + threadIdx.x;
  if(e >= EE) return;
  int d = dst[e];
  int pos = row_ptr[d] + atomicAdd(&cursor[d], 1);
  eidx[pos] = e;
}

// ---- head precompute: cvec[0:9]=rows 0..8 of enc_W@dec_W; cvec[9+b]=scalar
template<int M, typename TI>
__global__ void k_head(const int* __restrict__ flag,
                       const TI* __restrict__ encW, const TI* __restrict__ encb,
                       const TI* __restrict__ decW, const TI* __restrict__ decb,
                       const TI* __restrict__ te, float* __restrict__ cvec){
  if(*flag != M) return;
  __shared__ float c[19];
  int tid = threadIdx.x;
  if(tid < 18){ float s=0.f; for(int j=0;j<64;j++) s += ldin(encW,tid*64+j)*ldin(decW,j); c[tid]=s; }
  if(tid == 18){ float s=ldin(decb,0); for(int j=0;j<64;j++) s += ldin(encb,j)*ldin(decW,j); c[18]=s; }
  __syncthreads();
  if(tid < FF) cvec[tid] = c[tid];
  if(tid < BB){ float s=c[18]; for(int k=0;k<FF;k++) s += ldin(te,tid*FF+k)*c[9+k]; cvec[FF+tid]=s; }
}

// ---- conv1: 9 -> 64, fused CSR gather, wave per node, ELU ----------------
template<int M, typename TI, typename TA>
__global__ void k_conv1(const int* __restrict__ flag,
                        const TI* __restrict__ g, int t,
                        const int* __restrict__ rp, const int* __restrict__ eidx,
                        const int* __restrict__ esrc, const TI* __restrict__ ew,
                        const TI* __restrict__ Wl, const TI* __restrict__ bias,
                        const TI* __restrict__ Wr, TA* __restrict__ xa){
  if(*flag != M) return;
  __shared__ float sWl[FF*HH], sWr[FF*HH], sb[HH];
  int tid = threadIdx.x;
  for(int i=tid;i<FF*HH;i+=256){ sWl[i]=ldin(Wl,t*FF*HH+i); sWr[i]=ldin(Wr,t*FF*HH+i); }
  if(tid<HH) sb[tid]=ldin(bias,t*HH+tid);
  __syncthreads();
  int lane = tid & 63;
  int wid  = (blockIdx.x*256 + tid) >> 6;
  int nw   = gridDim.x*4;
  for(int bn = wid; bn < BB*NN; bn += nw){
    int n = bn % NN; int b = bn / NN;
    int r0 = rp[n], r1 = rp[n+1];
    float dg = fmaxf((float)(r1-r0), 1.0f);
    long gbase = ((long)(b*TT+t)*NN)*FF;
    float aggv = 0.f, xv = 0.f;
    if(lane < FF){
      xv = ldin(g, gbase + (long)n*FF + lane);
      for(int k=r0;k<r1;k++){
        int e = eidx[k];
        aggv += ldin(ew,e) * ldin(g, gbase + (long)esrc[e]*FF + lane);
      }
    }
    float accL=0.f, accR=0.f;
    #pragma unroll
    for(int f=0; f<FF; f++){
      float av = __shfl(aggv, f, 64);
      float xf = __shfl(xv,  f, 64);
      accL += av*sWl[f*HH+lane];
      accR += xf*sWr[f*HH+lane];
    }
    float acc = accL/dg + accR + sb[lane];
    stout(xa, (long)bn*HH+lane, acc>0.f ? acc : expm1f(acc));
  }
}

// ---- conv2: 64 -> 64, fused CSR gather, wave per node, ELU --------------
template<int M, typename TI, typename TA>
__global__ void k_conv2(const int* __restrict__ flag,
                        const TA* __restrict__ xin, int t,
                        const int* __restrict__ rp, const int* __restrict__ eidx,
                        const int* __restrict__ esrc, const TI* __restrict__ ew,
                        const TI* __restrict__ Wl, const TI* __restrict__ bias,
                        const TI* __restrict__ Wr, TA* __restrict__ xout){
  if(*flag != M) return;
  __shared__ float sWl[HH*HH], sWr[HH*HH], sb[HH];
  int tid = threadIdx.x;
  for(int i=tid;i<HH*HH;i+=256){ sWl[i]=ldin(Wl,t*HH*HH+i); sWr[i]=ldin(Wr,t*HH*HH+i); }
  if(tid<HH) sb[tid]=ldin(bias,t*HH+tid);
  __syncthreads();
  int lane = tid & 63;
  int wid  = (blockIdx.x*256 + tid) >> 6;
  int nw   = gridDim.x*4;
  for(int bn = wid; bn < BB*NN; bn += nw){
    int n = bn % NN; int b = bn / NN;
    int r0 = rp[n], r1 = rp[n+1];
    float dg = fmaxf((float)(r1-r0), 1.0f);
    float xv = ldin(xin, (long)bn*HH+lane);
    float aggv = 0.f;
    for(int k=r0;k<r1;k++){
      int e = eidx[k];
      aggv += ldin(ew,e) * ldin(xin, (long)(b*NN+esrc[e])*HH+lane);
    }
    aggv /= dg;
    float accL=0.f, accR=0.f;
    for(int i=0;i<HH;i++){
      float av = __shfl(aggv, i, 64);
      float xf = __shfl(xv,  i, 64);
      accL += av*sWl[i*HH+lane];
      accR += xf*sWr[i*HH+lane];
    }
    float acc = accL + accR + sb[lane];
    stout(xout, (long)bn*HH+lane, acc>0.f ? acc : expm1f(acc));
  }
}

// ---- conv3: 64 -> 9, fused CSR gather, wave per node, butterfly, ELU ----
template<int M, typename TI, typename TA>
__global__ void k_conv3(const int* __restrict__ flag,
                        const TA* __restrict__ xin, int t,
                        const int* __restrict__ rp, const int* __restrict__ eidx,
                        const int* __restrict__ esrc, const TI* __restrict__ ew,
                        const TI* __restrict__ Wl, const TI* __restrict__ bias,
                        const TI* __restrict__ Wr, float* __restrict__ x9){
  if(*flag != M) return;
  __shared__ float sWl[HH*FF], sWr[HH*FF], sb[FF];
  int tid = threadIdx.x;
  for(int i=tid;i<HH*FF;i+=256){ sWl[i]=ldin(Wl,t*HH*FF+i); sWr[i]=ldin(Wr,t*HH*FF+i); }
  if(tid<FF) sb[tid]=ldin(bias,t*FF+tid);
  __syncthreads();
  int lane = tid & 63;
  int wid  = (blockIdx.x*256 + tid) >> 6;
  int nw   = gridDim.x*4;
  for(int bn = wid; bn < BB*NN; bn += nw){
    int n = bn % NN; int b = bn / NN;
    int r0 = rp[n], r1 = rp[n+1];
    float dg = fmaxf((float)(r1-r0), 1.0f);
    float xv = ldin(xin, (long)bn*HH+lane);
    float aggv = 0.f;
    for(int k=r0;k<r1;k++){
      int e = eidx[k];
      aggv += ldin(ew,e) * ldin(xin, (long)(b*NN+esrc[e])*HH+lane);
    }
    aggv /= dg;
    float p[FF];
    #pragma unroll
    for(int f=0;f<FF;f++) p[f] = aggv*sWl[lane*FF+f] + xv*sWr[lane*FF+f];
    #pragma unroll
    for(int f=0;f<FF;f++){
      #pragma unroll
      for(int m=32;m>=1;m>>=1) p[f] += __shfl_xor(p[f], m, 64);
    }
    if(lane==0){
      #pragma unroll
      for(int f=0;f<FF;f++){
        float acc = p[f] + sb[f];
        x9[(long)bn*FF+f] = acc>0.f ? acc : expm1f(acc);
      }
    }
  }
}

// ---- GRU (9->9) + fused head + mask; one thread per (b,n) ---------------
template<int M, typename TI>
__global__ void k_gru_head(const int* __restrict__ flag,
                           const float* __restrict__ x9, int t,
                           const TI* __restrict__ Wih, const TI* __restrict__ Whh,
                           const TI* __restrict__ bih, const TI* __restrict__ bhh,
                           const float* __restrict__ hprev, float* __restrict__ hcur,
                           const float* __restrict__ cvec, const TI* __restrict__ g,
                           TI* __restrict__ out){
  if(*flag != M) return;
  __shared__ float sWi[FF*27], sWh[FF*27], sbi[27], sbh[27], sc[FF+BB];
  int tid = threadIdx.x;
  for(int i=tid;i<FF*27;i+=256){ sWi[i]=ldin(Wih,t*FF*27+i); sWh[i]=ldin(Whh,t*FF*27+i); }
  if(tid<27){ sbi[tid]=ldin(bih,t*27+tid); sbh[tid]=ldin(bhh,t*27+tid); }
  if(tid<FF+BB) sc[tid]=cvec[tid];
  __syncthreads();
  int bn = blockIdx.x*256 + tid;
  if(bn >= BB*NN) return;
  int n = bn % NN; int b = bn / NN;
  float x[FF], hp[FF];
  #pragma unroll
  for(int i=0;i<FF;i++){
    x[i]  = x9[(long)bn*FF+i];
    hp[i] = (t==0) ? 0.f : hprev[(long)bn*FF+i];
  }
  float h[FF];
  #pragma unroll
  for(int f=0;f<FF;f++){
    float gir=sbi[f], giz=sbi[9+f], gin=sbi[18+f];
    float ghr=sbh[f], ghz=sbh[9+f], ghn=sbh[18+f];
    #pragma unroll
    for(int i=0;i<FF;i++){
      gir += x[i]*sWi[i*27+f];   giz += x[i]*sWi[i*27+9+f];   gin += x[i]*sWi[i*27+18+f];
      ghr += hp[i]*sWh[i*27+f];  ghz += hp[i]*sWh[i*27+9+f];  ghn += hp[i]*sWh[i*27+18+f];
    }
    float r = 1.f/(1.f+__expf(-(gir+ghr)));
    float z = 1.f/(1.f+__expf(-(giz+ghz)));
    float nv = tanhf(gin + r*ghn);
    h[f] = (1.f-z)*nv + z*hp[f];
  }
  float acc = sc[FF+b];
  #pragma unroll
  for(int f=0;f<FF;f++){ hcur[(long)bn*FF+f] = h[f]; acc += h[f]*sc[f]; }
  long gi = (long)(b*TT+t)*NN + n;
  float m = (ldin(g, gi*FF) != 0.f) ? 1.f : 0.f;
  stout(out, gi, acc*m);
}

// ---- per-mode launch sequence -------------------------------------------
template<int M, typename TI, typename TA>
static void launch_mode(void* const* d_in, void* d_out,
                        int* flag, int* row_ptr, int* eidx,
                        float* cvec, float* x9, float* hbuf, TA* xa, TA* xb,
                        hipStream_t stream){
  const TI* g   = (const TI*)d_in[0];
  const TI* te  = (const TI*)d_in[1];
  const TI* ew  = (const TI*)d_in[3];
  const int* esrc = (const int*)d_in[4];
  const TI* W1l=(const TI*)d_in[6];  const TI* b1 =(const TI*)d_in[7];  const TI* W1r=(const TI*)d_in[8];
  const TI* W2l=(const TI*)d_in[9];  const TI* b2 =(const TI*)d_in[10]; const TI* W2r=(const TI*)d_in[11];
  const TI* W3l=(const TI*)d_in[12]; const TI* b3 =(const TI*)d_in[13]; const TI* W3r=(const TI*)d_in[14];
  const TI* Wih=(const TI*)d_in[15]; const TI* Whh=(const TI*)d_in[16];
  const TI* bih=(const TI*)d_in[17]; const TI* bhh=(const TI*)d_in[18];
  const TI* encW=(const TI*)d_in[19]; const TI* encb=(const TI*)d_in[20];
  const TI* decW=(const TI*)d_in[21]; const TI* decb=(const TI*)d_in[22];
  TI* out = (TI*)d_out;

  k_head<M,TI><<<1, 64, 0, stream>>>(flag, encW, encb, decW, decb, te, cvec);
  const int CB = 1024;
  for(int t=0; t<TT; t++){
    k_conv1<M,TI,TA><<<CB, 256, 0, stream>>>(flag, g, t, row_ptr, eidx, esrc, ew, W1l, b1, W1r, xa);
    k_conv2<M,TI,TA><<<CB, 256, 0, stream>>>(flag, xa, t, row_ptr, eidx, esrc, ew, W2l, b2, W2r, xb);
    k_conv3<M,TI,TA><<<CB, 256, 0, stream>>>(flag, xb, t, row_ptr, eidx, esrc, ew, W3l, b3, W3r, x9);
    float* hcur  = hbuf + (size_t)(t&1)*BB*NN*FF;
    float* hprev = hbuf + (size_t)((t+1)&1)*BB*NN*FF;
    k_gru_head<M,TI><<<(BB*NN+255)/256, 256, 0, stream>>>(flag, x9, t, Wih, Whh, bih, bhh,
                                                          hprev, hcur, cvec, g, out);
  }
}

template<typename TA>
static void run_all(void* const* d_in, void* d_out, void* d_ws, hipStream_t stream){
  char* base = (char*)d_ws;
  size_t off = 0;
  auto alloc = [&](size_t bytes)->char*{
    off = (off + 15) & ~(size_t)15;
    char* p = base + off; off += bytes; return p;
  };
  int*   flag    = (int*)  alloc(16);
  int*   row_ptr = (int*)  alloc((NN+1)*sizeof(int));
  int*   counts  = (int*)  alloc(NN*sizeof(int));      // reused as fill-cursor
  int*   eidx    = (int*)  alloc(EE*sizeof(int));
  float* cvec    = (float*)alloc(32*sizeof(float));
  float* x9      = (float*)alloc((size_t)BB*NN*FF*sizeof(float));
  float* hbuf    = (float*)alloc((size_t)2*BB*NN*FF*sizeof(float));
  TA*    xa      = (TA*)   alloc((size_t)BB*NN*HH*sizeof(TA));
  TA*    xb      = (TA*)   alloc((size_t)BB*NN*HH*sizeof(TA));

  const int* edst = (const int*)d_in[5];

  k_probe<<<1, 64, 0, stream>>>((const unsigned*)d_in[3], flag);
  hipMemsetAsync(counts, 0, NN*sizeof(int), stream);
  k_count<<<(EE+255)/256, 256, 0, stream>>>(edst, counts);
  k_scan<<<1, 256, 0, stream>>>(counts, row_ptr);
  hipMemsetAsync(counts, 0, NN*sizeof(int), stream);
  k_fill<<<(EE+255)/256, 256, 0, stream>>>(edst, row_ptr, counts, eidx);

  launch_mode<MODE_F32,  float,          TA>(d_in, d_out, flag, row_ptr, eidx, cvec, x9, hbuf, xa, xb, stream);
  launch_mode<MODE_BF16, __hip_bfloat16, TA>(d_in, d_out, flag, row_ptr, eidx, cvec, x9, hbuf, xa, xb, stream);
}

extern "C" void kernel_launch(void* const* d_in, const int* in_sizes, int n_in,
                              void* d_out, int out_size, void* d_ws, size_t ws_size,
                              hipStream_t stream){
  // fp32-activation layout needs ~25.9 MB; bf16-activation fallback ~15.6 MB.
  size_t fixed = 16 + 16 + (NN+1)*4 + 16 + NN*4 + 16 + EE*4 + 16 + 128 +
                 16 + (size_t)BB*NN*FF*4 + 16 + (size_t)2*BB*NN*FF*4 + 64;
  size_t need_f32 = fixed + (size_t)2*BB*NN*HH*sizeof(float) + 32;
  if(ws_size >= need_f32) run_all<float>(d_in, d_out, d_ws, stream);
  else                    run_all<__hip_bfloat16>(d_in, d_out, d_ws, stream);
}

// Round 5
// 5675.571 us; speedup vs baseline: 1.0991x; 1.0991x over previous
//
#include <hip/hip_runtime.h>
#include <hip/hip_bf16.h>

#define BB 2
#define TT 12
#define NN 20000
#define FF 9
#define HH 64
#define EE 200000

typedef __hip_bfloat16 bf;

__device__ __forceinline__ float lo2f(unsigned u){ unsigned v=u<<16; float f; __builtin_memcpy(&f,&v,4); return f; }
__device__ __forceinline__ float hi2f(unsigned u){ unsigned v=u&0xffff0000u; float f; __builtin_memcpy(&f,&v,4); return f; }
__device__ __forceinline__ unsigned short f2us(float f){ bf h=__float2bfloat16(f); unsigned short u; __builtin_memcpy(&u,&h,2); return u; }
__device__ __forceinline__ unsigned pack2(float a0, float a1){ return (unsigned)f2us(a0) | ((unsigned)f2us(a1)<<16); }
__device__ __forceinline__ float elu(float x){ return x>0.f ? x : expm1f(x); }

// ---- CSR build -----------------------------------------------------------
__global__ void k_count(const int* __restrict__ dst, int* __restrict__ counts){
  int e = blockIdx.x*256 + threadIdx.x;
  if(e < EE) atomicAdd(&counts[dst[e]], 1);
}

__global__ void k_scan(const int* __restrict__ counts, int* __restrict__ row_ptr){
  __shared__ int part[256];
  const int CH = 79;                       // 256*79 = 20224 >= 20000
  int t = threadIdx.x;
  int base = t*CH;
  int s = 0;
  for(int i=0;i<CH;i++){ int idx=base+i; if(idx<NN) s += counts[idx]; }
  part[t] = s; __syncthreads();
  for(int off=1; off<256; off<<=1){
    int v = (t>=off) ? part[t-off] : 0;
    __syncthreads();
    part[t] += v;
    __syncthreads();
  }
  int run = (t==0) ? 0 : part[t-1];
  for(int i=0;i<CH;i++){
    int idx=base+i;
    if(idx<NN){ run += counts[idx]; row_ptr[idx+1] = run; }
  }
  if(t==0) row_ptr[0] = 0;
}

// fill CSR-ordered src + weight streams
__global__ void k_fill(const int* __restrict__ dst, const int* __restrict__ src,
                       const float* __restrict__ ew, const int* __restrict__ row_ptr,
                       int* __restrict__ cursor, int* __restrict__ csrc, float* __restrict__ cw){
  int e = blockIdx.x*256 + threadIdx.x;
  if(e >= EE) return;
  int d = dst[e];
  int pos = row_ptr[d] + atomicAdd(&cursor[d], 1);
  csrc[pos] = src[e];
  cw[pos]   = ew[e];
}

// ---- head precompute: cvec[0:9]=rows 0..8 of enc_W@dec_W; cvec[9+b]=scalar
__global__ void k_head(const float* __restrict__ encW, const float* __restrict__ encb,
                       const float* __restrict__ decW, const float* __restrict__ decb,
                       const float* __restrict__ te, float* __restrict__ cvec){
  __shared__ float c[19];
  int tid = threadIdx.x;
  if(tid < 18){ float s=0.f; for(int j=0;j<64;j++) s += encW[tid*64+j]*decW[j]; c[tid]=s; }
  if(tid == 18){ float s=decb[0]; for(int j=0;j<64;j++) s += encb[j]*decW[j]; c[18]=s; }
  __syncthreads();
  if(tid < FF) cvec[tid] = c[tid];
  if(tid < BB){ float s=c[18]; for(int k=0;k<FF;k++) s += te[tid*FF+k]*c[9+k]; cvec[FF+tid]=s; }
}

// ---- conv1: 9 -> 64, both batches per wave, paired-u32 bf16 output ------
__global__ void k_conv1(const float* __restrict__ g, int t,
                        const int* __restrict__ rp, const int* __restrict__ csrc,
                        const float* __restrict__ cw,
                        const float* __restrict__ Wl, const float* __restrict__ bias,
                        const float* __restrict__ Wr, unsigned* __restrict__ xa){
  __shared__ float sWl[FF*HH], sWr[FF*HH], sb[HH];
  int tid = threadIdx.x;
  for(int i=tid;i<FF*HH;i+=256){ sWl[i]=Wl[t*FF*HH+i]; sWr[i]=Wr[t*FF*HH+i]; }
  if(tid<HH) sb[tid]=bias[t*HH+tid];
  __syncthreads();
  int lane = tid & 63;
  int half = lane>>5, l9 = lane&31;        // half = batch; lanes {0..8, 32..40} load
  bool act = l9 < FF;
  int wid = (blockIdx.x*256+tid)>>6, nw = gridDim.x*4;
  long gb = ((long)(half*TT+t)*NN)*FF;
  for(int n=wid; n<NN; n+=nw){
    int r0=rp[n], r1=rp[n+1];
    float dg = fmaxf((float)(r1-r0), 1.f);
    float xv=0.f, agg=0.f;
    if(act) xv = g[gb + (long)n*FF + l9];
    int s = 0; float w = 0.f;
    if(r0<r1){ s = csrc[r0]; w = cw[r0]; }
    for(int k=r0;k<r1;k++){
      int sn=0; float wn=0.f;
      if(k+1<r1){ sn = csrc[k+1]; wn = cw[k+1]; }
      if(act) agg += w * g[gb + (long)s*FF + l9];
      s = sn; w = wn;
    }
    agg /= dg;
    float a0 = sb[lane], a1 = sb[lane];
    #pragma unroll
    for(int f=0; f<FF; f++){
      float av0=__shfl(agg,f,64),    sv0=__shfl(xv,f,64);
      float av1=__shfl(agg,32+f,64), sv1=__shfl(xv,32+f,64);
      float wl=sWl[f*HH+lane], wr=sWr[f*HH+lane];
      a0 += av0*wl + sv0*wr;
      a1 += av1*wl + sv1*wr;
    }
    xa[n*HH+lane] = pack2(elu(a0), elu(a1));
  }
}

// ---- conv2: 64 -> 64, paired gather (one 256B row serves both batches) --
__global__ void k_conv2(const unsigned* __restrict__ xin, int t,
                        const int* __restrict__ rp, const int* __restrict__ csrc,
                        const float* __restrict__ cw,
                        const float* __restrict__ Wl, const float* __restrict__ bias,
                        const float* __restrict__ Wr, unsigned* __restrict__ xout){
  __shared__ float sWl[HH*HH], sWr[HH*HH], sb[HH];
  int tid = threadIdx.x;
  for(int i=tid;i<HH*HH;i+=256){ sWl[i]=Wl[t*HH*HH+i]; sWr[i]=Wr[t*HH*HH+i]; }
  if(tid<HH) sb[tid]=bias[t*HH+tid];
  __syncthreads();
  int lane = tid & 63;
  int wid = (blockIdx.x*256+tid)>>6, nw = gridDim.x*4;
  for(int n=wid; n<NN; n+=nw){
    int r0=rp[n], r1=rp[n+1];
    float dg = fmaxf((float)(r1-r0), 1.f);
    unsigned su = xin[n*HH+lane];
    float xv0 = lo2f(su), xv1 = hi2f(su);
    float g0=0.f, g1=0.f;
    int s = 0; float w = 0.f;
    if(r0<r1){ s = csrc[r0]; w = cw[r0]; }
    for(int k=r0;k<r1;k++){
      int sn=0; float wn=0.f;
      if(k+1<r1){ sn = csrc[k+1]; wn = cw[k+1]; }
      unsigned u = xin[s*HH+lane];
      g0 += w*lo2f(u); g1 += w*hi2f(u);
      s = sn; w = wn;
    }
    g0 /= dg; g1 /= dg;
    float a0 = sb[lane], a1 = sb[lane];
    #pragma unroll
    for(int i=0;i<HH;i++){
      float wl=sWl[i*HH+lane], wr=sWr[i*HH+lane];
      a0 += __shfl(g0,i,64)*wl + __shfl(xv0,i,64)*wr;
      a1 += __shfl(g1,i,64)*wl + __shfl(xv1,i,64)*wr;
    }
    xout[n*HH+lane] = pack2(elu(a0), elu(a1));
  }
}

// ---- conv3 (64->9) + GRU(9->9) + head + mask, fused ---------------------
__global__ void k_conv3g(const unsigned* __restrict__ xin, int t,
                         const int* __restrict__ rp, const int* __restrict__ csrc,
                         const float* __restrict__ cw,
                         const float* __restrict__ Wl, const float* __restrict__ bias,
                         const float* __restrict__ Wr,
                         const float* __restrict__ Wih, const float* __restrict__ Whh,
                         const float* __restrict__ bih, const float* __restrict__ bhh,
                         const float* __restrict__ cvec, const float* __restrict__ g,
                         float* __restrict__ h, float* __restrict__ out){
  __shared__ float sWl[HH*FF], sWr[HH*FF], sb[FF];
  __shared__ float sWi[FF*27], sWh[FF*27], sbi[27], sbh[27], sc[FF+BB];
  int tid = threadIdx.x;
  for(int i=tid;i<HH*FF;i+=256){ sWl[i]=Wl[t*HH*FF+i]; sWr[i]=Wr[t*HH*FF+i]; }
  for(int i=tid;i<FF*27;i+=256){ sWi[i]=Wih[t*FF*27+i]; sWh[i]=Whh[t*FF*27+i]; }
  if(tid<27){ sbi[tid]=bih[t*27+tid]; sbh[tid]=bhh[t*27+tid]; }
  if(tid<FF) sb[tid]=bias[t*FF+tid];
  if(tid<FF+BB) sc[tid]=cvec[tid];
  __syncthreads();
  int lane = tid & 63;
  int wid = (blockIdx.x*256+tid)>>6, nw = gridDim.x*4;
  for(int n=wid; n<NN; n+=nw){
    int r0=rp[n], r1=rp[n+1];
    float dg = fmaxf((float)(r1-r0), 1.f);
    unsigned su = xin[n*HH+lane];
    float xv0 = lo2f(su), xv1 = hi2f(su);
    float g0=0.f, g1=0.f;
    int s = 0; float w = 0.f;
    if(r0<r1){ s = csrc[r0]; w = cw[r0]; }
    for(int k=r0;k<r1;k++){
      int sn=0; float wn=0.f;
      if(k+1<r1){ sn = csrc[k+1]; wn = cw[k+1]; }
      unsigned u = xin[s*HH+lane];
      g0 += w*lo2f(u); g1 += w*hi2f(u);
      s = sn; w = wn;
    }
    g0 /= dg; g1 /= dg;
    float p0[FF], p1[FF];
    #pragma unroll
    for(int f=0;f<FF;f++){
      float wl=sWl[lane*FF+f], wr=sWr[lane*FF+f];
      p0[f] = g0*wl + xv0*wr;
      p1[f] = g1*wl + xv1*wr;
    }
    #pragma unroll
    for(int f=0;f<FF;f++){
      #pragma unroll
      for(int m=32;m>=1;m>>=1){ p0[f] += __shfl_xor(p0[f], m, 64); p1[f] += __shfl_xor(p1[f], m, 64); }
    }
    // all lanes hold the full conv3 9-vector for both batches
    float x0[FF], x1[FF];
    #pragma unroll
    for(int f=0;f<FF;f++){ x0[f] = elu(p0[f]+sb[f]); x1[f] = elu(p1[f]+sb[f]); }

    if(lane < 18){
      int b = (lane >= FF) ? 1 : 0;
      int f = lane - FF*b;
      long hidx = (long)(n*BB + b)*FF + f;
      float hp_own = (t==0) ? 0.f : h[hidx];
      float hp[FF];
      #pragma unroll
      for(int i=0;i<FF;i++) hp[i] = __shfl(hp_own, b*FF+i, 64);
      float gir=sbi[f], giz=sbi[9+f], gin=sbi[18+f];
      float ghr=sbh[f], ghz=sbh[9+f], ghn=sbh[18+f];
      #pragma unroll
      for(int i=0;i<FF;i++){
        float xi = b ? x1[i] : x0[i];
        gir += xi*sWi[i*27+f];  giz += xi*sWi[i*27+9+f];  gin += xi*sWi[i*27+18+f];
        ghr += hp[i]*sWh[i*27+f]; ghz += hp[i]*sWh[i*27+9+f]; ghn += hp[i]*sWh[i*27+18+f];
      }
      float r = 1.f/(1.f+__expf(-(gir+ghr)));
      float z = 1.f/(1.f+__expf(-(giz+ghz)));
      float nv = tanhf(gin + r*ghn);
      float hv = (1.f-z)*nv + z*hp_own;
      h[hidx] = hv;
      float v = hv*sc[f];
      float hs = v;
      #pragma unroll
      for(int j=1;j<FF;j++) hs += __shfl(v, b*FF+j, 64);
      if(f==0){
        long gi = (long)(b*TT+t)*NN + n;
        float m = (g[gi*FF] != 0.f) ? 1.f : 0.f;
        out[gi] = (hs + sc[FF+b])*m;
      }
    }
  }
}

extern "C" void kernel_launch(void* const* d_in, const int* in_sizes, int n_in,
                              void* d_out, int out_size, void* d_ws, size_t ws_size,
                              hipStream_t stream){
  const float* g    = (const float*)d_in[0];
  const float* te   = (const float*)d_in[1];
  const float* ew   = (const float*)d_in[3];
  const int* esrc = (const int*)d_in[4];
  const int* edst = (const int*)d_in[5];
  const float* W1l=(const float*)d_in[6];  const float* b1 =(const float*)d_in[7];  const float* W1r=(const float*)d_in[8];
  const float* W2l=(const float*)d_in[9];  const float* b2 =(const float*)d_in[10]; const float* W2r=(const float*)d_in[11];
  const float* W3l=(const float*)d_in[12]; const float* b3 =(const float*)d_in[13]; const float* W3r=(const float*)d_in[14];
  const float* Wih=(const float*)d_in[15]; const float* Whh=(const float*)d_in[16];
  const float* bih=(const float*)d_in[17]; const float* bhh=(const float*)d_in[18];
  const float* encW=(const float*)d_in[19]; const float* encb=(const float*)d_in[20];
  const float* decW=(const float*)d_in[21]; const float* decb=(const float*)d_in[22];
  float* out = (float*)d_out;

  // workspace layout, ~13.5 MB (round 3 proved ws_size >= 15.5 MB)
  char* base = (char*)d_ws;
  size_t off = 0;
  auto alloc = [&](size_t bytes)->char*{
    off = (off + 255) & ~(size_t)255;
    char* p = base + off; off += bytes; return p;
  };
  int*   row_ptr = (int*)  alloc((NN+1)*sizeof(int));
  int*   counts  = (int*)  alloc(NN*sizeof(int));      // reused as fill-cursor
  int*   csrc    = (int*)  alloc(EE*sizeof(int));
  float* cw      = (float*)alloc(EE*sizeof(float));
  float* cvec    = (float*)alloc(32*sizeof(float));
  float* h       = (float*)alloc((size_t)NN*BB*FF*sizeof(float));
  unsigned* xa   = (unsigned*)alloc((size_t)NN*HH*sizeof(unsigned));
  unsigned* xb   = (unsigned*)alloc((size_t)NN*HH*sizeof(unsigned));

  hipMemsetAsync(counts, 0, NN*sizeof(int), stream);
  k_count<<<(EE+255)/256, 256, 0, stream>>>(edst, counts);
  k_scan<<<1, 256, 0, stream>>>(counts, row_ptr);
  hipMemsetAsync(counts, 0, NN*sizeof(int), stream);
  k_fill<<<(EE+255)/256, 256, 0, stream>>>(edst, esrc, ew, row_ptr, counts, csrc, cw);
  k_head<<<1, 64, 0, stream>>>(encW, encb, decW, decb, te, cvec);

  const int CB = 1024;   // 4 waves/block; conv2 LDS 33KB -> 4 blocks/CU
  for(int t=0; t<TT; t++){
    k_conv1 <<<CB, 256, 0, stream>>>(g, t, row_ptr, csrc, cw, W1l, b1, W1r, xa);
    k_conv2 <<<CB, 256, 0, stream>>>(xa, t, row_ptr, csrc, cw, W2l, b2, W2r, xb);
    k_conv3g<<<CB, 256, 0, stream>>>(xb, t, row_ptr, csrc, cw, W3l, b3, W3r,
                                     Wih, Whh, bih, bhh, cvec, g, h, out);
  }
}

// Round 6
// 5289.395 us; speedup vs baseline: 1.1793x; 1.0730x over previous
//
#include <hip/hip_runtime.h>
#include <hip/hip_bf16.h>

#define BB 2
#define TT 12
#define NN 20000
#define FF 9
#define HH 64
#define EE 200000

typedef __hip_bfloat16 bf;

__device__ __forceinline__ float lo2f(unsigned u){ unsigned v=u<<16; float f; __builtin_memcpy(&f,&v,4); return f; }
__device__ __forceinline__ float hi2f(unsigned u){ unsigned v=u&0xffff0000u; float f; __builtin_memcpy(&f,&v,4); return f; }
__device__ __forceinline__ unsigned short f2us(float f){ bf h=__float2bfloat16(f); unsigned short u; __builtin_memcpy(&u,&h,2); return u; }
__device__ __forceinline__ unsigned pack2(float a0, float a1){ return (unsigned)f2us(a0) | ((unsigned)f2us(a1)<<16); }
__device__ __forceinline__ float elu(float x){ return x>0.f ? x : expm1f(x); }

// ---- CSR build -----------------------------------------------------------
__global__ void k_count(const int* __restrict__ dst, int* __restrict__ counts){
  int e = blockIdx.x*256 + threadIdx.x;
  if(e < EE) atomicAdd(&counts[dst[e]], 1);
}

__global__ void k_scan(const int* __restrict__ counts, int* __restrict__ row_ptr){
  __shared__ int part[256];
  const int CH = 79;                       // 256*79 = 20224 >= 20000
  int t = threadIdx.x;
  int base = t*CH;
  int s = 0;
  for(int i=0;i<CH;i++){ int idx=base+i; if(idx<NN) s += counts[idx]; }
  part[t] = s; __syncthreads();
  for(int off=1; off<256; off<<=1){
    int v = (t>=off) ? part[t-off] : 0;
    __syncthreads();
    part[t] += v;
    __syncthreads();
  }
  int run = (t==0) ? 0 : part[t-1];
  for(int i=0;i<CH;i++){
    int idx=base+i;
    if(idx<NN){ run += counts[idx]; row_ptr[idx+1] = run; }
  }
  if(t==0) row_ptr[0] = 0;
}

__global__ void k_fill(const int* __restrict__ dst, const int* __restrict__ src,
                       const float* __restrict__ ew, const int* __restrict__ row_ptr,
                       int* __restrict__ cursor, int* __restrict__ csrc, float* __restrict__ cw){
  int e = blockIdx.x*256 + threadIdx.x;
  if(e >= EE) return;
  int d = dst[e];
  int pos = row_ptr[d] + atomicAdd(&cursor[d], 1);
  csrc[pos] = src[e];
  cw[pos]   = ew[e];
}

// ---- head precompute -----------------------------------------------------
__global__ void k_head(const float* __restrict__ encW, const float* __restrict__ encb,
                       const float* __restrict__ decW, const float* __restrict__ decb,
                       const float* __restrict__ te, float* __restrict__ cvec){
  __shared__ float c[19];
  int tid = threadIdx.x;
  if(tid < 18){ float s=0.f; for(int j=0;j<64;j++) s += encW[tid*64+j]*decW[j]; c[tid]=s; }
  if(tid == 18){ float s=decb[0]; for(int j=0;j<64;j++) s += encb[j]*decW[j]; c[18]=s; }
  __syncthreads();
  if(tid < FF) cvec[tid] = c[tid];
  if(tid < BB){ float s=c[18]; for(int k=0;k<FF;k++) s += te[tid*FF+k]*c[9+k]; cvec[FF+tid]=s; }
}

// ---- conv1: 9 -> 64, lane-parallel metadata, 4 gathers in flight --------
__global__ void k_conv1(const float* __restrict__ g, int t,
                        const int* __restrict__ rp, const int* __restrict__ csrc,
                        const float* __restrict__ cw,
                        const float* __restrict__ Wl, const float* __restrict__ bias,
                        const float* __restrict__ Wr, unsigned* __restrict__ xa){
  __shared__ float sWl[FF*HH], sWr[FF*HH], sb[HH];
  int tid = threadIdx.x;
  for(int i=tid;i<FF*HH;i+=256){ sWl[i]=Wl[t*FF*HH+i]; sWr[i]=Wr[t*FF*HH+i]; }
  if(tid<HH) sb[tid]=bias[t*HH+tid];
  __syncthreads();
  int lane = tid & 63;
  int half = lane>>5, l9 = lane&31;        // half = batch; lanes {0..8, 32..40} gather
  bool act = l9 < FF;
  int wid = (blockIdx.x*256+tid)>>6, nw = gridDim.x*4;
  long gb = ((long)(half*TT+t)*NN)*FF;
  for(int n=wid; n<NN; n+=nw){
    int r0=rp[n], r1=rp[n+1];
    float dg = fmaxf((float)(r1-r0), 1.f);
    float xv=0.f, agg=0.f;
    if(act) xv = g[gb + (long)n*FF + l9];
    for(int base=r0; base<r1; base+=64){
      int cnt = min(64, r1-base);
      int ms = 0; float mw = 0.f;
      if(lane < cnt){ ms = csrc[base+lane]; mw = cw[base+lane]; }
      for(int k=0;k<cnt;k+=4){
        int   s0=__shfl(ms,k,64),   s1=__shfl(ms,k+1,64),   s2=__shfl(ms,k+2,64),   s3=__shfl(ms,k+3,64);
        float w0=__shfl(mw,k,64),   w1=__shfl(mw,k+1,64),   w2=__shfl(mw,k+2,64),   w3=__shfl(mw,k+3,64);
        if(act){
          float v0=g[gb+(long)s0*FF+l9], v1=g[gb+(long)s1*FF+l9];
          float v2=g[gb+(long)s2*FF+l9], v3=g[gb+(long)s3*FF+l9];
          agg += w0*v0 + w1*v1 + w2*v2 + w3*v3;
        }
      }
    }
    agg /= dg;
    float a0 = sb[lane], a1 = sb[lane];
    #pragma unroll
    for(int f=0; f<FF; f++){
      float av0=__shfl(agg,f,64),    sv0=__shfl(xv,f,64);
      float av1=__shfl(agg,32+f,64), sv1=__shfl(xv,32+f,64);
      float wl=sWl[f*HH+lane], wr=sWr[f*HH+lane];
      a0 += av0*wl + sv0*wr;
      a1 += av1*wl + sv1*wr;
    }
    xa[n*HH+lane] = pack2(elu(a0), elu(a1));
  }
}

// ---- conv2: 64 -> 64, lane-parallel metadata, 4 gathers in flight -------
__global__ void k_conv2(const unsigned* __restrict__ xin, int t,
                        const int* __restrict__ rp, const int* __restrict__ csrc,
                        const float* __restrict__ cw,
                        const float* __restrict__ Wl, const float* __restrict__ bias,
                        const float* __restrict__ Wr, unsigned* __restrict__ xout){
  __shared__ float sWl[HH*HH], sWr[HH*HH], sb[HH];
  int tid = threadIdx.x;
  for(int i=tid;i<HH*HH;i+=256){ sWl[i]=Wl[t*HH*HH+i]; sWr[i]=Wr[t*HH*HH+i]; }
  if(tid<HH) sb[tid]=bias[t*HH+tid];
  __syncthreads();
  int lane = tid & 63;
  int wid = (blockIdx.x*256+tid)>>6, nw = gridDim.x*4;
  for(int n=wid; n<NN; n+=nw){
    int r0=rp[n], r1=rp[n+1];
    float dg = fmaxf((float)(r1-r0), 1.f);
    unsigned su = xin[n*HH+lane];
    float xv0 = lo2f(su), xv1 = hi2f(su);
    float g0=0.f, g1=0.f;
    for(int base=r0; base<r1; base+=64){
      int cnt = min(64, r1-base);
      int ms = 0; float mw = 0.f;
      if(lane < cnt){ ms = csrc[base+lane]; mw = cw[base+lane]; }
      for(int k=0;k<cnt;k+=4){
        int   s0=__shfl(ms,k,64),   s1=__shfl(ms,k+1,64),   s2=__shfl(ms,k+2,64),   s3=__shfl(ms,k+3,64);
        float w0=__shfl(mw,k,64),   w1=__shfl(mw,k+1,64),   w2=__shfl(mw,k+2,64),   w3=__shfl(mw,k+3,64);
        unsigned u0=xin[s0*HH+lane], u1=xin[s1*HH+lane];
        unsigned u2=xin[s2*HH+lane], u3=xin[s3*HH+lane];
        g0 += w0*lo2f(u0) + w1*lo2f(u1) + w2*lo2f(u2) + w3*lo2f(u3);
        g1 += w0*hi2f(u0) + w1*hi2f(u1) + w2*hi2f(u2) + w3*hi2f(u3);
      }
    }
    g0 /= dg; g1 /= dg;
    float a0 = sb[lane], a1 = sb[lane];
    #pragma unroll
    for(int i=0;i<HH;i++){
      float wl=sWl[i*HH+lane], wr=sWr[i*HH+lane];
      a0 += __shfl(g0,i,64)*wl + __shfl(xv0,i,64)*wr;
      a1 += __shfl(g1,i,64)*wl + __shfl(xv1,i,64)*wr;
    }
    xout[n*HH+lane] = pack2(elu(a0), elu(a1));
  }
}

// ---- conv3 (64->9) + GRU(9->9) + head + mask, fused ---------------------
__global__ void k_conv3g(const unsigned* __restrict__ xin, int t,
                         const int* __restrict__ rp, const int* __restrict__ csrc,
                         const float* __restrict__ cw,
                         const float* __restrict__ Wl, const float* __restrict__ bias,
                         const float* __restrict__ Wr,
                         const float* __restrict__ Wih, const float* __restrict__ Whh,
                         const float* __restrict__ bih, const float* __restrict__ bhh,
                         const float* __restrict__ cvec, const float* __restrict__ g,
                         float* __restrict__ h, float* __restrict__ out){
  __shared__ float sWl[HH*FF], sWr[HH*FF], sb[FF];
  __shared__ float sWi[FF*27], sWh[FF*27], sbi[27], sbh[27], sc[FF+BB];
  int tid = threadIdx.x;
  for(int i=tid;i<HH*FF;i+=256){ sWl[i]=Wl[t*HH*FF+i]; sWr[i]=Wr[t*HH*FF+i]; }
  for(int i=tid;i<FF*27;i+=256){ sWi[i]=Wih[t*FF*27+i]; sWh[i]=Whh[t*FF*27+i]; }
  if(tid<27){ sbi[tid]=bih[t*27+tid]; sbh[tid]=bhh[t*27+tid]; }
  if(tid<FF) sb[tid]=bias[t*FF+tid];
  if(tid<FF+BB) sc[tid]=cvec[tid];
  __syncthreads();
  int lane = tid & 63;
  int wid = (blockIdx.x*256+tid)>>6, nw = gridDim.x*4;
  for(int n=wid; n<NN; n+=nw){
    int r0=rp[n], r1=rp[n+1];
    float dg = fmaxf((float)(r1-r0), 1.f);
    unsigned su = xin[n*HH+lane];
    float xv0 = lo2f(su), xv1 = hi2f(su);
    float g0=0.f, g1=0.f;
    for(int base=r0; base<r1; base+=64){
      int cnt = min(64, r1-base);
      int ms = 0; float mw = 0.f;
      if(lane < cnt){ ms = csrc[base+lane]; mw = cw[base+lane]; }
      for(int k=0;k<cnt;k+=4){
        int   s0=__shfl(ms,k,64),   s1=__shfl(ms,k+1,64),   s2=__shfl(ms,k+2,64),   s3=__shfl(ms,k+3,64);
        float w0=__shfl(mw,k,64),   w1=__shfl(mw,k+1,64),   w2=__shfl(mw,k+2,64),   w3=__shfl(mw,k+3,64);
        unsigned u0=xin[s0*HH+lane], u1=xin[s1*HH+lane];
        unsigned u2=xin[s2*HH+lane], u3=xin[s3*HH+lane];
        g0 += w0*lo2f(u0) + w1*lo2f(u1) + w2*lo2f(u2) + w3*lo2f(u3);
        g1 += w0*hi2f(u0) + w1*hi2f(u1) + w2*hi2f(u2) + w3*hi2f(u3);
      }
    }
    g0 /= dg; g1 /= dg;
    float p0[FF], p1[FF];
    #pragma unroll
    for(int f=0;f<FF;f++){
      float wl=sWl[lane*FF+f], wr=sWr[lane*FF+f];
      p0[f] = g0*wl + xv0*wr;
      p1[f] = g1*wl + xv1*wr;
    }
    #pragma unroll
    for(int f=0;f<FF;f++){
      #pragma unroll
      for(int m=32;m>=1;m>>=1){ p0[f] += __shfl_xor(p0[f], m, 64); p1[f] += __shfl_xor(p1[f], m, 64); }
    }
    float x0[FF], x1[FF];
    #pragma unroll
    for(int f=0;f<FF;f++){ x0[f] = elu(p0[f]+sb[f]); x1[f] = elu(p1[f]+sb[f]); }

    if(lane < 18){
      int b = (lane >= FF) ? 1 : 0;
      int f = lane - FF*b;
      long hidx = (long)(n*BB + b)*FF + f;
      float hp_own = (t==0) ? 0.f : h[hidx];
      float hp[FF];
      #pragma unroll
      for(int i=0;i<FF;i++) hp[i] = __shfl(hp_own, b*FF+i, 64);
      float gir=sbi[f], giz=sbi[9+f], gin=sbi[18+f];
      float ghr=sbh[f], ghz=sbh[9+f], ghn=sbh[18+f];
      #pragma unroll
      for(int i=0;i<FF;i++){
        float xi = b ? x1[i] : x0[i];
        gir += xi*sWi[i*27+f];  giz += xi*sWi[i*27+9+f];  gin += xi*sWi[i*27+18+f];
        ghr += hp[i]*sWh[i*27+f]; ghz += hp[i]*sWh[i*27+9+f]; ghn += hp[i]*sWh[i*27+18+f];
      }
      float r = 1.f/(1.f+__expf(-(gir+ghr)));
      float z = 1.f/(1.f+__expf(-(giz+ghz)));
      float nv = tanhf(gin + r*ghn);
      float hv = (1.f-z)*nv + z*hp_own;
      h[hidx] = hv;
      float v = hv*sc[f];
      float hs = v;
      #pragma unroll
      for(int j=1;j<FF;j++) hs += __shfl(v, b*FF+j, 64);
      if(f==0){
        long gi = (long)(b*TT+t)*NN + n;
        float m = (g[gi*FF] != 0.f) ? 1.f : 0.f;
        out[gi] = (hs + sc[FF+b])*m;
      }
    }
  }
}

extern "C" void kernel_launch(void* const* d_in, const int* in_sizes, int n_in,
                              void* d_out, int out_size, void* d_ws, size_t ws_size,
                              hipStream_t stream){
  const float* g    = (const float*)d_in[0];
  const float* te   = (const float*)d_in[1];
  const float* ew   = (const float*)d_in[3];
  const int* esrc = (const int*)d_in[4];
  const int* edst = (const int*)d_in[5];
  const float* W1l=(const float*)d_in[6];  const float* b1 =(const float*)d_in[7];  const float* W1r=(const float*)d_in[8];
  const float* W2l=(const float*)d_in[9];  const float* b2 =(const float*)d_in[10]; const float* W2r=(const float*)d_in[11];
  const float* W3l=(const float*)d_in[12]; const float* b3 =(const float*)d_in[13]; const float* W3r=(const float*)d_in[14];
  const float* Wih=(const float*)d_in[15]; const float* Whh=(const float*)d_in[16];
  const float* bih=(const float*)d_in[17]; const float* bhh=(const float*)d_in[18];
  const float* encW=(const float*)d_in[19]; const float* encb=(const float*)d_in[20];
  const float* decW=(const float*)d_in[21]; const float* decb=(const float*)d_in[22];
  float* out = (float*)d_out;

  char* base = (char*)d_ws;
  size_t off = 0;
  auto alloc = [&](size_t bytes)->char*{
    off = (off + 255) & ~(size_t)255;
    char* p = base + off; off += bytes; return p;
  };
  int*   row_ptr = (int*)  alloc((NN+1)*sizeof(int));
  int*   counts  = (int*)  alloc(NN*sizeof(int));
  int*   csrc    = (int*)  alloc(EE*sizeof(int));
  float* cw      = (float*)alloc(EE*sizeof(float));
  float* cvec    = (float*)alloc(32*sizeof(float));
  float* h       = (float*)alloc((size_t)NN*BB*FF*sizeof(float));
  unsigned* xa   = (unsigned*)alloc((size_t)NN*HH*sizeof(unsigned));
  unsigned* xb   = (unsigned*)alloc((size_t)NN*HH*sizeof(unsigned));

  hipMemsetAsync(counts, 0, NN*sizeof(int), stream);
  k_count<<<(EE+255)/256, 256, 0, stream>>>(edst, counts);
  k_scan<<<1, 256, 0, stream>>>(counts, row_ptr);
  hipMemsetAsync(counts, 0, NN*sizeof(int), stream);
  k_fill<<<(EE+255)/256, 256, 0, stream>>>(edst, esrc, ew, row_ptr, counts, csrc, cw);
  k_head<<<1, 64, 0, stream>>>(encW, encb, decW, decb, te, cvec);

  const int CB = 1024;   // 4 waves/block; conv2 LDS 33KB -> 4 blocks/CU
  for(int t=0; t<TT; t++){
    k_conv1 <<<CB, 256, 0, stream>>>(g, t, row_ptr, csrc, cw, W1l, b1, W1r, xa);
    k_conv2 <<<CB, 256, 0, stream>>>(xa, t, row_ptr, csrc, cw, W2l, b2, W2r, xb);
    k_conv3g<<<CB, 256, 0, stream>>>(xb, t, row_ptr, csrc, cw, W3l, b3, W3r,
                                     Wih, Whh, bih, bhh, cvec, g, h, out);
  }
}

// Round 7
// 4561.578 us; speedup vs baseline: 1.3675x; 1.1596x over previous
//
#include <hip/hip_runtime.h>
#include <hip/hip_bf16.h>

#define BB 2
#define TT 12
#define NN 20000
#define FF 9
#define HH 64
#define EE 200000

typedef __hip_bfloat16 bf;

__device__ __forceinline__ float lo2f(unsigned u){ unsigned v=u<<16; float f; __builtin_memcpy(&f,&v,4); return f; }
__device__ __forceinline__ float hi2f(unsigned u){ unsigned v=u&0xffff0000u; float f; __builtin_memcpy(&f,&v,4); return f; }
__device__ __forceinline__ unsigned short f2us(float f){ bf h=__float2bfloat16(f); unsigned short u; __builtin_memcpy(&u,&h,2); return u; }
__device__ __forceinline__ unsigned pack2(float a0, float a1){ return (unsigned)f2us(a0) | ((unsigned)f2us(a1)<<16); }
__device__ __forceinline__ float elu(float x){ return x>0.f ? x : expm1f(x); }

// ---- CSR build -----------------------------------------------------------
__global__ void k_count(const int* __restrict__ dst, int* __restrict__ counts){
  int e = blockIdx.x*256 + threadIdx.x;
  if(e < EE) atomicAdd(&counts[dst[e]], 1);
}

__global__ void k_scan(const int* __restrict__ counts, int* __restrict__ row_ptr){
  __shared__ int part[256];
  const int CH = 79;                       // 256*79 = 20224 >= 20000
  int t = threadIdx.x;
  int base = t*CH;
  int s = 0;
  for(int i=0;i<CH;i++){ int idx=base+i; if(idx<NN) s += counts[idx]; }
  part[t] = s; __syncthreads();
  for(int off=1; off<256; off<<=1){
    int v = (t>=off) ? part[t-off] : 0;
    __syncthreads();
    part[t] += v;
    __syncthreads();
  }
  int run = (t==0) ? 0 : part[t-1];
  for(int i=0;i<CH;i++){
    int idx=base+i;
    if(idx<NN){ run += counts[idx]; row_ptr[idx+1] = run; }
  }
  if(t==0) row_ptr[0] = 0;
}

__global__ void k_fill(const int* __restrict__ dst, const int* __restrict__ src,
                       const float* __restrict__ ew, const int* __restrict__ row_ptr,
                       int* __restrict__ cursor, int* __restrict__ csrc, float* __restrict__ cw){
  int e = blockIdx.x*256 + threadIdx.x;
  if(e >= EE) return;
  int d = dst[e];
  int pos = row_ptr[d] + atomicAdd(&cursor[d], 1);
  csrc[pos] = src[e];
  cw[pos]   = ew[e];
}

// ---- head precompute -----------------------------------------------------
__global__ void k_head(const float* __restrict__ encW, const float* __restrict__ encb,
                       const float* __restrict__ decW, const float* __restrict__ decb,
                       const float* __restrict__ te, float* __restrict__ cvec){
  __shared__ float c[19];
  int tid = threadIdx.x;
  if(tid < 18){ float s=0.f; for(int j=0;j<64;j++) s += encW[tid*64+j]*decW[j]; c[tid]=s; }
  if(tid == 18){ float s=decb[0]; for(int j=0;j<64;j++) s += encb[j]*decW[j]; c[18]=s; }
  __syncthreads();
  if(tid < FF) cvec[tid] = c[tid];
  if(tid < BB){ float s=c[18]; for(int k=0;k<FF;k++) s += te[tid*FF+k]*c[9+k]; cvec[FF+tid]=s; }
}

// ---- conv1: 9 -> 64 (unchanged from round 6; t-slices are L2-resident) --
__global__ void k_conv1(const float* __restrict__ g, int t,
                        const int* __restrict__ rp, const int* __restrict__ csrc,
                        const float* __restrict__ cw,
                        const float* __restrict__ Wl, const float* __restrict__ bias,
                        const float* __restrict__ Wr, unsigned* __restrict__ xa){
  __shared__ float sWl[FF*HH], sWr[FF*HH], sb[HH];
  int tid = threadIdx.x;
  for(int i=tid;i<FF*HH;i+=256){ sWl[i]=Wl[t*FF*HH+i]; sWr[i]=Wr[t*FF*HH+i]; }
  if(tid<HH) sb[tid]=bias[t*HH+tid];
  __syncthreads();
  int lane = tid & 63;
  int half = lane>>5, l9 = lane&31;        // half = batch; lanes {0..8, 32..40} gather
  bool act = l9 < FF;
  int wid = (blockIdx.x*256+tid)>>6, nw = gridDim.x*4;
  long gb = ((long)(half*TT+t)*NN)*FF;
  for(int n=wid; n<NN; n+=nw){
    int r0=rp[n], r1=rp[n+1];
    float dg = fmaxf((float)(r1-r0), 1.f);
    float xv=0.f, agg=0.f;
    if(act) xv = g[gb + (long)n*FF + l9];
    for(int base=r0; base<r1; base+=64){
      int cnt = min(64, r1-base);
      int ms = 0; float mw = 0.f;
      if(lane < cnt){ ms = csrc[base+lane]; mw = cw[base+lane]; }
      for(int k=0;k<cnt;k+=4){
        int   s0=__shfl(ms,k,64),   s1=__shfl(ms,k+1,64),   s2=__shfl(ms,k+2,64),   s3=__shfl(ms,k+3,64);
        float w0=__shfl(mw,k,64),   w1=__shfl(mw,k+1,64),   w2=__shfl(mw,k+2,64),   w3=__shfl(mw,k+3,64);
        if(act){
          float v0=g[gb+(long)s0*FF+l9], v1=g[gb+(long)s1*FF+l9];
          float v2=g[gb+(long)s2*FF+l9], v3=g[gb+(long)s3*FF+l9];
          agg += w0*v0 + w1*v1 + w2*v2 + w3*v3;
        }
      }
    }
    agg /= dg;
    float a0 = sb[lane], a1 = sb[lane];
    #pragma unroll
    for(int f=0; f<FF; f++){
      float av0=__shfl(agg,f,64),    sv0=__shfl(xv,f,64);
      float av1=__shfl(agg,32+f,64), sv1=__shfl(xv,32+f,64);
      float wl=sWl[f*HH+lane], wr=sWr[f*HH+lane];
      a0 += av0*wl + sv0*wr;
      a1 += av1*wl + sv1*wr;
    }
    xa[n*HH+lane] = pack2(elu(a0), elu(a1));
  }
}

// ---- conv2: 64 -> 64, dwordx4 gather: 4 edges/wave-instr, 16 lanes/row --
__global__ void k_conv2(const unsigned* __restrict__ xin, int t,
                        const int* __restrict__ rp, const int* __restrict__ csrc,
                        const float* __restrict__ cw,
                        const float* __restrict__ Wl, const float* __restrict__ bias,
                        const float* __restrict__ Wr, unsigned* __restrict__ xout){
  __shared__ float sWl[HH*HH], sWr[HH*HH], sb[HH];
  int tid = threadIdx.x;
  for(int i=tid;i<HH*HH;i+=256){ sWl[i]=Wl[t*HH*HH+i]; sWr[i]=Wr[t*HH*HH+i]; }
  if(tid<HH) sb[tid]=bias[t*HH+tid];
  __syncthreads();
  int lane = tid & 63;
  int grp  = lane >> 4;                    // edge group 0..3
  int sub  = lane & 15;                    // 16-B chunk within row
  int wid = (blockIdx.x*256+tid)>>6, nw = gridDim.x*4;
  for(int n=wid; n<NN; n+=nw){
    int r0=rp[n], r1=rp[n+1];
    float dg = fmaxf((float)(r1-r0), 1.f);
    unsigned su = xin[n*HH+lane];
    float xv0 = lo2f(su), xv1 = hi2f(su);
    float p0[4]={0.f,0.f,0.f,0.f}, p1[4]={0.f,0.f,0.f,0.f};
    for(int base=r0; base<r1; base+=64){
      int cnt = min(64, r1-base);
      int ms = 0; float mw = 0.f;
      if(lane < cnt){ ms = csrc[base+lane]; mw = cw[base+lane]; }
      for(int k=0;k<cnt;k+=4){
        int   sg = __shfl(ms, k+grp, 64);  // per-lane src (OOB lanes: s=0,w=0)
        float wg = __shfl(mw, k+grp, 64);
        const uint4 v = *reinterpret_cast<const uint4*>(xin + (size_t)sg*HH + (sub<<2));
        p0[0]+=wg*lo2f(v.x); p1[0]+=wg*hi2f(v.x);
        p0[1]+=wg*lo2f(v.y); p1[1]+=wg*hi2f(v.y);
        p0[2]+=wg*lo2f(v.z); p1[2]+=wg*hi2f(v.z);
        p0[3]+=wg*lo2f(v.w); p1[3]+=wg*hi2f(v.w);
      }
    }
    #pragma unroll
    for(int q=0;q<4;q++){
      p0[q] += __shfl_xor(p0[q],16,64); p1[q] += __shfl_xor(p1[q],16,64);
      p0[q] += __shfl_xor(p0[q],32,64); p1[q] += __shfl_xor(p1[q],32,64);
      p0[q] /= dg; p1[q] /= dg;
    }
    // lanes 0..15 hold agg features 4*lane+q
    float a0 = sb[lane], a1 = sb[lane];
    #pragma unroll
    for(int i=0;i<HH;i++){
      float av0=__shfl(p0[i&3], i>>2, 64);
      float av1=__shfl(p1[i&3], i>>2, 64);
      float sv0=__shfl(xv0, i, 64);
      float sv1=__shfl(xv1, i, 64);
      float wl=sWl[i*HH+lane], wr=sWr[i*HH+lane];
      a0 += av0*wl + sv0*wr;
      a1 += av1*wl + sv1*wr;
    }
    xout[n*HH+lane] = pack2(elu(a0), elu(a1));
  }
}

// ---- conv3 (64->9) + GRU(9->9) + head + mask, dwordx4 gather ------------
__global__ void k_conv3g(const unsigned* __restrict__ xin, int t,
                         const int* __restrict__ rp, const int* __restrict__ csrc,
                         const float* __restrict__ cw,
                         const float* __restrict__ Wl, const float* __restrict__ bias,
                         const float* __restrict__ Wr,
                         const float* __restrict__ Wih, const float* __restrict__ Whh,
                         const float* __restrict__ bih, const float* __restrict__ bhh,
                         const float* __restrict__ cvec, const float* __restrict__ g,
                         float* __restrict__ h, float* __restrict__ out){
  __shared__ float sWl[HH*FF], sWr[HH*FF], sb[FF];
  __shared__ float sWi[FF*27], sWh[FF*27], sbi[27], sbh[27], sc[FF+BB];
  int tid = threadIdx.x;
  for(int i=tid;i<HH*FF;i+=256){ sWl[i]=Wl[t*HH*FF+i]; sWr[i]=Wr[t*HH*FF+i]; }
  for(int i=tid;i<FF*27;i+=256){ sWi[i]=Wih[t*FF*27+i]; sWh[i]=Whh[t*FF*27+i]; }
  if(tid<27){ sbi[tid]=bih[t*27+tid]; sbh[tid]=bhh[t*27+tid]; }
  if(tid<FF) sb[tid]=bias[t*FF+tid];
  if(tid<FF+BB) sc[tid]=cvec[tid];
  __syncthreads();
  int lane = tid & 63;
  int grp  = lane >> 4;
  int sub  = lane & 15;
  int wid = (blockIdx.x*256+tid)>>6, nw = gridDim.x*4;
  for(int n=wid; n<NN; n+=nw){
    int r0=rp[n], r1=rp[n+1];
    float dg = fmaxf((float)(r1-r0), 1.f);
    unsigned su = xin[n*HH+lane];
    float xv0 = lo2f(su), xv1 = hi2f(su);
    float p0[4]={0.f,0.f,0.f,0.f}, p1[4]={0.f,0.f,0.f,0.f};
    for(int base=r0; base<r1; base+=64){
      int cnt = min(64, r1-base);
      int ms = 0; float mw = 0.f;
      if(lane < cnt){ ms = csrc[base+lane]; mw = cw[base+lane]; }
      for(int k=0;k<cnt;k+=4){
        int   sg = __shfl(ms, k+grp, 64);
        float wg = __shfl(mw, k+grp, 64);
        const uint4 v = *reinterpret_cast<const uint4*>(xin + (size_t)sg*HH + (sub<<2));
        p0[0]+=wg*lo2f(v.x); p1[0]+=wg*hi2f(v.x);
        p0[1]+=wg*lo2f(v.y); p1[1]+=wg*hi2f(v.y);
        p0[2]+=wg*lo2f(v.z); p1[2]+=wg*hi2f(v.z);
        p0[3]+=wg*lo2f(v.w); p1[3]+=wg*hi2f(v.w);
      }
    }
    #pragma unroll
    for(int q=0;q<4;q++){
      p0[q] += __shfl_xor(p0[q],16,64); p1[q] += __shfl_xor(p1[q],16,64);
      p0[q] += __shfl_xor(p0[q],32,64); p1[q] += __shfl_xor(p1[q],32,64);
      p0[q] /= dg; p1[q] /= dg;
    }
    // dense 64->9: lane<16 contributes its 4 agg features; all lanes their xv
    float part0[FF], part1[FF];
    bool own = (lane < 16);
    #pragma unroll
    for(int f=0;f<FF;f++){
      float s0 = xv0*sWr[lane*FF+f];
      float s1 = xv1*sWr[lane*FF+f];
      if(own){
        #pragma unroll
        for(int q=0;q<4;q++){
          int i = (lane<<2)+q;
          s0 += p0[q]*sWl[i*FF+f];
          s1 += p1[q]*sWl[i*FF+f];
        }
      }
      part0[f]=s0; part1[f]=s1;
    }
    #pragma unroll
    for(int f=0;f<FF;f++){
      #pragma unroll
      for(int m=32;m>=1;m>>=1){ part0[f] += __shfl_xor(part0[f], m, 64); part1[f] += __shfl_xor(part1[f], m, 64); }
    }
    float x0[FF], x1[FF];
    #pragma unroll
    for(int f=0;f<FF;f++){ x0[f] = elu(part0[f]+sb[f]); x1[f] = elu(part1[f]+sb[f]); }

    if(lane < 18){
      int b = (lane >= FF) ? 1 : 0;
      int f = lane - FF*b;
      long hidx = (long)(n*BB + b)*FF + f;
      float hp_own = (t==0) ? 0.f : h[hidx];
      float hp[FF];
      #pragma unroll
      for(int i=0;i<FF;i++) hp[i] = __shfl(hp_own, b*FF+i, 64);
      float gir=sbi[f], giz=sbi[9+f], gin=sbi[18+f];
      float ghr=sbh[f], ghz=sbh[9+f], ghn=sbh[18+f];
      #pragma unroll
      for(int i=0;i<FF;i++){
        float xi = b ? x1[i] : x0[i];
        gir += xi*sWi[i*27+f];  giz += xi*sWi[i*27+9+f];  gin += xi*sWi[i*27+18+f];
        ghr += hp[i]*sWh[i*27+f]; ghz += hp[i]*sWh[i*27+9+f]; ghn += hp[i]*sWh[i*27+18+f];
      }
      float r = 1.f/(1.f+__expf(-(gir+ghr)));
      float z = 1.f/(1.f+__expf(-(giz+ghz)));
      float nv = tanhf(gin + r*ghn);
      float hv = (1.f-z)*nv + z*hp_own;
      h[hidx] = hv;
      float v = hv*sc[f];
      float hs = v;
      #pragma unroll
      for(int j=1;j<FF;j++) hs += __shfl(v, b*FF+j, 64);
      if(f==0){
        long gi = (long)(b*TT+t)*NN + n;
        float m = (g[gi*FF] != 0.f) ? 1.f : 0.f;
        out[gi] = (hs + sc[FF+b])*m;
      }
    }
  }
}

extern "C" void kernel_launch(void* const* d_in, const int* in_sizes, int n_in,
                              void* d_out, int out_size, void* d_ws, size_t ws_size,
                              hipStream_t stream){
  const float* g    = (const float*)d_in[0];
  const float* te   = (const float*)d_in[1];
  const float* ew   = (const float*)d_in[3];
  const int* esrc = (const int*)d_in[4];
  const int* edst = (const int*)d_in[5];
  const float* W1l=(const float*)d_in[6];  const float* b1 =(const float*)d_in[7];  const float* W1r=(const float*)d_in[8];
  const float* W2l=(const float*)d_in[9];  const float* b2 =(const float*)d_in[10]; const float* W2r=(const float*)d_in[11];
  const float* W3l=(const float*)d_in[12]; const float* b3 =(const float*)d_in[13]; const float* W3r=(const float*)d_in[14];
  const float* Wih=(const float*)d_in[15]; const float* Whh=(const float*)d_in[16];
  const float* bih=(const float*)d_in[17]; const float* bhh=(const float*)d_in[18];
  const float* encW=(const float*)d_in[19]; const float* encb=(const float*)d_in[20];
  const float* decW=(const float*)d_in[21]; const float* decb=(const float*)d_in[22];
  float* out = (float*)d_out;

  char* base = (char*)d_ws;
  size_t off = 0;
  auto alloc = [&](size_t bytes)->char*{
    off = (off + 255) & ~(size_t)255;
    char* p = base + off; off += bytes; return p;
  };
  int*   row_ptr = (int*)  alloc((NN+1)*sizeof(int));
  int*   counts  = (int*)  alloc(NN*sizeof(int));
  int*   csrc    = (int*)  alloc(EE*sizeof(int));
  float* cw      = (float*)alloc(EE*sizeof(float));
  float* cvec    = (float*)alloc(32*sizeof(float));
  float* h       = (float*)alloc((size_t)NN*BB*FF*sizeof(float));
  unsigned* xa   = (unsigned*)alloc((size_t)NN*HH*sizeof(unsigned));
  unsigned* xb   = (unsigned*)alloc((size_t)NN*HH*sizeof(unsigned));

  hipMemsetAsync(counts, 0, NN*sizeof(int), stream);
  k_count<<<(EE+255)/256, 256, 0, stream>>>(edst, counts);
  k_scan<<<1, 256, 0, stream>>>(counts, row_ptr);
  hipMemsetAsync(counts, 0, NN*sizeof(int), stream);
  k_fill<<<(EE+255)/256, 256, 0, stream>>>(edst, esrc, ew, row_ptr, counts, csrc, cw);
  k_head<<<1, 64, 0, stream>>>(encW, encb, decW, decb, te, cvec);

  const int CB = 1024;   // 4 waves/block; conv2 LDS 33KB -> 4 blocks/CU
  for(int t=0; t<TT; t++){
    k_conv1 <<<CB, 256, 0, stream>>>(g, t, row_ptr, csrc, cw, W1l, b1, W1r, xa);
    k_conv2 <<<CB, 256, 0, stream>>>(xa, t, row_ptr, csrc, cw, W2l, b2, W2r, xb);
    k_conv3g<<<CB, 256, 0, stream>>>(xb, t, row_ptr, csrc, cw, W3l, b3, W3r,
                                     Wih, Whh, bih, bhh, cvec, g, h, out);
  }
}